// Round 18
// baseline (46.548 us; speedup 1.0000x reference)
//
#include <hip/hip_runtime.h>

// Policy MLP via split-precision bf16 MFMA (round 18: 4-stream intra-wave
// software pipeline -- T15 mechanism).
// B=131072, D=32, L=40 hidden + final 32->1.
//
// r9-r17 invariance (44-48us across conversion impls, LDS feeds, occupancy,
// prefetch, stagger) says the wall is the per-wave serial dataflow:
// MFMA block -> split block -> next MFMA block. This round changes the GRAPH:
// each wave runs FOUR independent 16-col streams through the layers in an
// 8-slot rotation  M_A s_C M_B s_D M_C s_A M_D s_B  -- every split is >=3
// slots from its producer and consumer MFMA blocks, so VALU split work of
// one stream overlaps the MFMA execution of others deterministically
// (MFMA and VALU are separate pipes). All streams share the layer's weight
// fragments (one LDS read set per wave-layer). C=64 -> 2048 waves, 512-thr
// blocks, 1 block/CU (157KB LDS), 2 waves/SIMD -- enough, since overlap is
// now intra-wave.
//
// Math per layer per stream: acc = Whi*xhi (C=bias); += Wlo*xhi; += Whi*xlo
// pi(g,j) = 4g+j (j<4) | 16+4g+(j-4) on both A and B => D feeds next B
// in-lane; truncation split via v_perm_b32 (hi's error carried by lo).

#define NB 131072
#define DD 32
#define NL 40
#define BIAS_BYTES ((NL + 1) * 32 * 4)       // 5248, compact fp32 bias
#define WTAB_OFF   BIAS_BYTES
#define WTAB_BYTES ((NL + 1) * 4 * 64 * 16)  // 167936
#define LDS_LAYERS 38
#define LDS_BYTES  (BIAS_BYTES + LDS_LAYERS * 4096)  // 160896 <= 163840

typedef short bf16x8 __attribute__((ext_vector_type(8)));
typedef float f32x4 __attribute__((ext_vector_type(4)));

union Frag { int4 q; int i[4]; bf16x8 v; };
union BFrag { float4 q; f32x4 v; };

__device__ inline unsigned f2bf(float f) {  // fp32 -> bf16 bits, RNE
  unsigned u = __float_as_uint(f);
  return (u + 0x7fffu + ((u >> 16) & 1u)) >> 16;
}
__device__ inline float bf2f(unsigned s) { return __int_as_float((int)(s << 16)); }

// ---- table build ----------------------------------------------------------
// d_ws layout: [bias compact 5248 B][wtab 41 layers x 4096 B].
// wtab[l][p][lane]: p=0: W[m][pi] hi, p=1: W[16+m][pi] hi, p=2/3: lo parts.
__global__ __launch_bounds__(64) void build_tables(
    const float* __restrict__ Wh, const float* __restrict__ bh,
    const float* __restrict__ Wout, const float* __restrict__ bout,
    char* __restrict__ ws) {
  const int l = blockIdx.x;      // 0..40 (40 == output layer)
  const int lane = threadIdx.x;  // 0..63
  const int m = lane & 15, g = lane >> 4;
  int4* wtab = (int4*)(ws + WTAB_OFF);
  float* bc = (float*)ws;
  for (int p = 0; p < 4; ++p) {
    const int row = (p & 1) ? (16 + m) : m;
    const bool lopart = (p >= 2);
    int wds[4];
    for (int w = 0; w < 4; ++w) {
      unsigned wd = 0;
      for (int e = 0; e < 2; ++e) {
        const int j = 2 * w + e;
        const int k = (j < 4) ? (4 * g + j) : (16 + 4 * g + (j - 4));  // pi
        float v;
        if (l < NL) v = Wh[(l * 32 + row) * 32 + k];
        else        v = (row == 0) ? Wout[k] : 0.f;  // final: row0 = W_out
        unsigned hi = f2bf(v);
        unsigned val = lopart ? f2bf(v - bf2f(hi)) : hi;
        wd |= val << (16 * e);
      }
      wds[w] = (int)wd;
    }
    wtab[(l * 4 + p) * 64 + lane] = make_int4(wds[0], wds[1], wds[2], wds[3]);
  }
  if (lane < 32) {  // compact bias, one float per output row
    float bv = (l < NL) ? bh[l * 32 + lane] : ((lane == 0) ? bout[0] : 0.f);
    bc[l * 32 + lane] = bv;
  }
}

// ---- main kernel ----------------------------------------------------------
// Truncation split: hi = packed high-halves of (a,b) via one v_perm_b32;
// lo = packed high-halves of the exact residuals.
__device__ inline void split2(float a, float b, int& hi, int& lo) {
  const unsigned ia = __float_as_uint(a), ib = __float_as_uint(b);
  hi = (int)__builtin_amdgcn_perm(ia, ib, 0x03020706u);
  const float ha = __int_as_float((int)(ia & 0xffff0000u));
  const float hb = __int_as_float((int)(ib & 0xffff0000u));
  const float la = a - ha, lb = b - hb;  // exact
  lo = (int)__builtin_amdgcn_perm(__float_as_uint(la), __float_as_uint(lb),
                                  0x03020706u);
}

#define MFMA16(A, B, C) __builtin_amdgcn_mfma_f32_16x16x32_bf16((A), (B), (C), 0, 0, 0)

// 6-MFMA hidden-layer block for one 16-col stream (2 accs, 3-deep chains).
#define MFMA_BLK(bhiX, bloX, aX0, aX1, P)                \
  aX0 = MFMA16(Wf[P][0].v, bhiX.v, Cf[P][0].v);          \
  aX1 = MFMA16(Wf[P][1].v, bhiX.v, Cf[P][1].v);          \
  aX0 = MFMA16(Wf[P][2].v, bhiX.v, aX0);                 \
  aX1 = MFMA16(Wf[P][3].v, bhiX.v, aX1);                 \
  aX0 = MFMA16(Wf[P][0].v, bloX.v, aX0);                 \
  aX1 = MFMA16(Wf[P][1].v, bloX.v, aX1);

// relu + trunc-split of one stream's accs -> its next-layer B frags.
#define SPLIT_BLK(aX0, aX1, bhiX, bloX)                                      \
  split2(fmaxf(aX0[0], 0.f), fmaxf(aX0[1], 0.f), bhiX.i[0], bloX.i[0]);      \
  split2(fmaxf(aX0[2], 0.f), fmaxf(aX0[3], 0.f), bhiX.i[1], bloX.i[1]);      \
  split2(fmaxf(aX1[0], 0.f), fmaxf(aX1[1], 0.f), bhiX.i[2], bloX.i[2]);      \
  split2(fmaxf(aX1[2], 0.f), fmaxf(aX1[3], 0.f), bhiX.i[3], bloX.i[3]);

#define PREFETCH(LP, P)                                                      \
  {                                                                          \
    const int4* src_ = ((LP) < LDS_LAYERS) ? lw : gw;                        \
    Wf[P][0].q = src_[(LP) * 256 + 0];                                       \
    Wf[P][1].q = src_[(LP) * 256 + 64];                                      \
    Wf[P][2].q = src_[(LP) * 256 + 128];                                     \
    Wf[P][3].q = src_[(LP) * 256 + 192];                                     \
    Cf[P][0].q = *(const float4*)(bc + (LP) * 32 + 4 * g);                   \
    Cf[P][1].q = *(const float4*)(bc + (LP) * 32 + 16 + 4 * g);              \
  }

__global__ __launch_bounds__(512, 2) void policy_mfma(
    const float* __restrict__ state, const char* __restrict__ tab,
    float* __restrict__ out) {
  extern __shared__ char smem[];
  const int tid = threadIdx.x;
  const int lane = tid & 63;
  const int n = lane & 15, g = lane >> 4;
  const int wid = blockIdx.x * 8 + (tid >> 6);
  const int bbase = wid * 64;  // 64 batch cols per wave = 4 x 16-col streams

  // ---- stage bias + 38 layers of weights into LDS (~157 KB, one-time) ----
  {
    const int4* src = (const int4*)tab;
    int4* dst = (int4*)smem;
    for (int i = tid; i < LDS_BYTES / 16; i += 512) dst[i] = src[i];
  }

  // Layer-0 B frags for the 4 streams (global reads; overlap staging)
  Frag bhiA, bloA, bhiB, bloB, bhiC, bloC, bhiD, bloD;
#define LOADX(bhiX, bloX, T)                                     \
  {                                                              \
    const float* xr = state + (size_t)(bbase + 16 * (T) + n) * DD; \
    float4 xa = *(const float4*)(xr + 4 * g);                    \
    float4 xc = *(const float4*)(xr + 16 + 4 * g);               \
    split2(xa.x, xa.y, bhiX.i[0], bloX.i[0]);                    \
    split2(xa.z, xa.w, bhiX.i[1], bloX.i[1]);                    \
    split2(xc.x, xc.y, bhiX.i[2], bloX.i[2]);                    \
    split2(xc.z, xc.w, bhiX.i[3], bloX.i[3]);                    \
  }
  LOADX(bhiA, bloA, 0)
  LOADX(bhiB, bloB, 1)
  LOADX(bhiC, bloC, 2)
  LOADX(bhiD, bloD, 3)

  __syncthreads();  // LDS tables ready

  const int4* lw = (const int4*)(smem + WTAB_OFF) + lane;  // LDS weights l<38
  const float* bc = (const float*)smem;                     // LDS bias, all l
  const int4* gw = (const int4*)(tab + WTAB_OFF) + lane;    // global l>=38

  Frag Wf[2][4];
  BFrag Cf[2][2];
  f32x4 aA0, aA1, aB0, aB1, aC0, aC1, aD0, aD1;

  // ---- peeled layer 0: all 4 streams' MFMA blocks (no splits yet) ----
  PREFETCH(0, 0)
  MFMA_BLK(bhiA, bloA, aA0, aA1, 0)
  MFMA_BLK(bhiB, bloB, aB0, aB1, 0)
  PREFETCH(1, 1)
  MFMA_BLK(bhiC, bloC, aC0, aC1, 0)
  MFMA_BLK(bhiD, bloD, aD0, aD1, 0)

  // ---- layers 1..39: 8-slot rotation, fully unrolled ----
#pragma unroll
  for (int l = 1; l < NL; ++l) {
    const int cur = l & 1, nxt = cur ^ 1;
    MFMA_BLK(bhiA, bloA, aA0, aA1, cur)   // slot0: M_A(l)
    SPLIT_BLK(aC0, aC1, bhiC, bloC)       // slot1: s_C (layer l-1 acc)
    MFMA_BLK(bhiB, bloB, aB0, aB1, cur)   // slot2: M_B(l)
    PREFETCH(l + 1, nxt)                  //        (layer l+1 frags)
    SPLIT_BLK(aD0, aD1, bhiD, bloD)       // slot3: s_D (layer l-1 acc)
    MFMA_BLK(bhiC, bloC, aC0, aC1, cur)   // slot4: M_C(l)
    SPLIT_BLK(aA0, aA1, bhiA, bloA)       // slot5: s_A (layer l acc)
    MFMA_BLK(bhiD, bloD, aD0, aD1, cur)   // slot6: M_D(l)
    SPLIT_BLK(aB0, aB1, bhiB, bloB)       // slot7: s_B (layer l acc)
  }

  // ---- epilogue: finish C/D splits, then final layer (parity 0 holds l=40:
  // W rows 16-31 zero -> only frags 0 (hi) / 2 (lo) + bias c0; row0 = W_out).
  SPLIT_BLK(aC0, aC1, bhiC, bloC)
  SPLIT_BLK(aD0, aD1, bhiD, bloD)

  float resA, resB, resC, resD;
#define FINAL_BLK(bhiX, bloX, resX)                   \
  {                                                   \
    f32x4 a = MFMA16(Wf[0][0].v, bhiX.v, Cf[0][0].v); \
    a = MFMA16(Wf[0][2].v, bhiX.v, a);                \
    a = MFMA16(Wf[0][0].v, bloX.v, a);                \
    resX = a[0];                                      \
  }
  FINAL_BLK(bhiA, bloA, resA)
  FINAL_BLK(bhiB, bloB, resB)
  FINAL_BLK(bhiC, bloC, resC)
  FINAL_BLK(bhiD, bloD, resD)

  if (lane < 16) {
    out[bbase + n] = resA;
    out[bbase + 16 + n] = resB;
    out[bbase + 32 + n] = resC;
    out[bbase + 48 + n] = resD;
  }
}

extern "C" void kernel_launch(void* const* d_in, const int* in_sizes, int n_in,
                              void* d_out, int out_size, void* d_ws, size_t ws_size,
                              hipStream_t stream) {
  const float* state = (const float*)d_in[0];
  const float* Wh    = (const float*)d_in[1];
  const float* bh    = (const float*)d_in[2];
  const float* Wout  = (const float*)d_in[3];
  const float* bout  = (const float*)d_in[4];
  float* out = (float*)d_out;

  build_tables<<<NL + 1, 64, 0, stream>>>(Wh, bh, Wout, bout, (char*)d_ws);

  // 131072/64 = 2048 waves; 512-thr blocks (8 waves) -> 256 blocks = 1/CU.
  policy_mfma<<<256, 512, LDS_BYTES, stream>>>(state, (const char*)d_ws, out);
}

// Round 19
// 44.994 us; speedup vs baseline: 1.0345x; 1.0345x over previous
//
#include <hip/hip_runtime.h>

// Policy MLP via split-precision bf16 MFMA (round 19: PINNED prefetch).
// B=131072, D=32, L=40 hidden + final 32->1.
//
// Round-19 change vs round 13 (single variable): the register prefetch of
// layer l+1's fragments is PINNED at the bottom of iteration l with an
// empty asm volatile "+v" constraint on the loaded values (rule #17
// keep-alive). Evidence: r13/r18 VGPR_Count stayed 36-52 -- the compiler
// SANK all source-level prefetches back to just-before-use, so each
// wave-layer pays LDS queue+latency on the critical path (the invariant
// ~1000 cyc/SIMD-layer that occupancy/feed/stagger never moved). The pin
// forces the ds_reads to complete by the end of iteration l: their wait
// lands after ~500 cyc of independent MFMA+split work, fully hidden, and
// the loads can no longer sink into iteration l+1.
//
// Base (r13): C=32 cols/wave, 16 waves/CU (1024-thr block, 1 block/CU via
// 157KB LDS), layers 0-37 + all bias in LDS, 38-40 via L1.
//
// Math per layer: acc = Whi*xhi (C=bias); += Wlo*xhi; += Whi*xlo
// pi(g,j) = 4g+j (j<4) | 16+4g+(j-4) on both A and B => D feeds next B
// in-lane; truncation split via v_perm_b32 (hi's error carried by lo).

#define NB 131072
#define DD 32
#define NL 40
#define BIAS_BYTES ((NL + 1) * 32 * 4)       // 5248, compact fp32 bias
#define WTAB_OFF   BIAS_BYTES
#define WTAB_BYTES ((NL + 1) * 4 * 64 * 16)  // 167936
#define LDS_LAYERS 38
#define LDS_BYTES  (BIAS_BYTES + LDS_LAYERS * 4096)  // 160896 <= 163840

typedef short bf16x8 __attribute__((ext_vector_type(8)));
typedef float f32x4 __attribute__((ext_vector_type(4)));
typedef int i32x4 __attribute__((ext_vector_type(4)));

union Frag { i32x4 q; int i[4]; bf16x8 v; };
union BFrag { f32x4 v; float f[4]; };

__device__ inline unsigned f2bf(float f) {  // fp32 -> bf16 bits, RNE
  unsigned u = __float_as_uint(f);
  return (u + 0x7fffu + ((u >> 16) & 1u)) >> 16;
}
__device__ inline float bf2f(unsigned s) { return __int_as_float((int)(s << 16)); }

// ---- table build ----------------------------------------------------------
// d_ws layout: [bias compact 5248 B][wtab 41 layers x 4096 B].
// wtab[l][p][lane]: p=0: W[m][pi] hi, p=1: W[16+m][pi] hi, p=2/3: lo parts.
__global__ __launch_bounds__(64) void build_tables(
    const float* __restrict__ Wh, const float* __restrict__ bh,
    const float* __restrict__ Wout, const float* __restrict__ bout,
    char* __restrict__ ws) {
  const int l = blockIdx.x;      // 0..40 (40 == output layer)
  const int lane = threadIdx.x;  // 0..63
  const int m = lane & 15, g = lane >> 4;
  int4* wtab = (int4*)(ws + WTAB_OFF);
  float* bc = (float*)ws;
  for (int p = 0; p < 4; ++p) {
    const int row = (p & 1) ? (16 + m) : m;
    const bool lopart = (p >= 2);
    int wds[4];
    for (int w = 0; w < 4; ++w) {
      unsigned wd = 0;
      for (int e = 0; e < 2; ++e) {
        const int j = 2 * w + e;
        const int k = (j < 4) ? (4 * g + j) : (16 + 4 * g + (j - 4));  // pi
        float v;
        if (l < NL) v = Wh[(l * 32 + row) * 32 + k];
        else        v = (row == 0) ? Wout[k] : 0.f;  // final: row0 = W_out
        unsigned hi = f2bf(v);
        unsigned val = lopart ? f2bf(v - bf2f(hi)) : hi;
        wd |= val << (16 * e);
      }
      wds[w] = (int)wd;
    }
    wtab[(l * 4 + p) * 64 + lane] = make_int4(wds[0], wds[1], wds[2], wds[3]);
  }
  if (lane < 32) {  // compact bias, one float per output row
    float bv = (l < NL) ? bh[l * 32 + lane] : ((lane == 0) ? bout[0] : 0.f);
    bc[l * 32 + lane] = bv;
  }
}

// ---- main kernel ----------------------------------------------------------
// Truncation split: hi = packed high-halves of (a,b) via one v_perm_b32;
// lo = packed high-halves of the exact residuals.
__device__ inline void split2(float a, float b, int& hi, int& lo) {
  const unsigned ia = __float_as_uint(a), ib = __float_as_uint(b);
  hi = (int)__builtin_amdgcn_perm(ia, ib, 0x03020706u);
  const float ha = __int_as_float((int)(ia & 0xffff0000u));
  const float hb = __int_as_float((int)(ib & 0xffff0000u));
  const float la = a - ha, lb = b - hb;  // exact
  lo = (int)__builtin_amdgcn_perm(__float_as_uint(la), __float_as_uint(lb),
                                  0x03020706u);
}

#define MFMA16(A, B, C) __builtin_amdgcn_mfma_f32_16x16x32_bf16((A), (B), (C), 0, 0, 0)

__global__ __launch_bounds__(1024, 4) void policy_mfma(
    const float* __restrict__ state, const char* __restrict__ tab,
    float* __restrict__ out) {
  extern __shared__ char smem[];
  const int tid = threadIdx.x;
  const int lane = tid & 63;
  const int n = lane & 15, g = lane >> 4;
  const int wid = blockIdx.x * 16 + (tid >> 6);
  const int bbase = wid * 32;  // 32 batch cols per wave (2 x 16-col tiles)

  // ---- stage bias + 38 layers of weights into LDS (~157 KB, one-time) ----
  {
    const int4* src = (const int4*)tab;
    int4* dst = (int4*)smem;
    for (int i = tid; i < LDS_BYTES / 16; i += 1024) dst[i] = src[i];
  }

  // Layer-0 B frags from state (no LDS dependency; overlaps staging)
  Frag bhi[2], blo[2];
#pragma unroll
  for (int t = 0; t < 2; ++t) {
    const float* xr = state + (size_t)(bbase + 16 * t + n) * DD;
    float4 xa = *(const float4*)(xr + 4 * g);
    float4 xc = *(const float4*)(xr + 16 + 4 * g);
    split2(xa.x, xa.y, bhi[t].i[0], blo[t].i[0]);
    split2(xa.z, xa.w, bhi[t].i[1], blo[t].i[1]);
    split2(xc.x, xc.y, bhi[t].i[2], blo[t].i[2]);
    split2(xc.z, xc.w, bhi[t].i[3], blo[t].i[3]);
  }

  __syncthreads();  // LDS tables ready

  const i32x4* lw = (const i32x4*)(smem + WTAB_OFF) + lane;  // LDS weights
  const float* bc = (const float*)smem;                      // LDS bias, all l
  const i32x4* gw = (const i32x4*)(tab + WTAB_OFF) + lane;   // global l>=38

  // Double-buffered register prefetch (parity index; full unroll => static).
  Frag Wf[2][4];
  BFrag Cf[2][2];
  Wf[0][0].q = lw[0];
  Wf[0][1].q = lw[64];
  Wf[0][2].q = lw[128];
  Wf[0][3].q = lw[192];
  Cf[0][0].v = *(const f32x4*)(bc + 4 * g);
  Cf[0][1].v = *(const f32x4*)(bc + 16 + 4 * g);

#pragma unroll
  for (int l = 0; l < NL; ++l) {
    const int cur = l & 1, nxt = cur ^ 1;

    // ---- prefetch layer l+1 fragments into the other buffer ----
    {
      const int lp = l + 1;
      const i32x4* src = (lp < LDS_LAYERS) ? lw : gw;  // compile-time per iter
      Wf[nxt][0].q = src[lp * 256 + 0];
      Wf[nxt][1].q = src[lp * 256 + 64];
      Wf[nxt][2].q = src[lp * 256 + 128];
      Wf[nxt][3].q = src[lp * 256 + 192];
      Cf[nxt][0].v = *(const f32x4*)(bc + lp * 32 + 4 * g);
      Cf[nxt][1].v = *(const f32x4*)(bc + lp * 32 + 16 + 4 * g);
    }

    // ---- compute layer l: 4 independent 3-deep chains ----
    f32x4 a00 = MFMA16(Wf[cur][0].v, bhi[0].v, Cf[cur][0].v);
    f32x4 a01 = MFMA16(Wf[cur][1].v, bhi[0].v, Cf[cur][1].v);
    f32x4 a10 = MFMA16(Wf[cur][0].v, bhi[1].v, Cf[cur][0].v);
    f32x4 a11 = MFMA16(Wf[cur][1].v, bhi[1].v, Cf[cur][1].v);
    a00 = MFMA16(Wf[cur][2].v, bhi[0].v, a00);
    a01 = MFMA16(Wf[cur][3].v, bhi[0].v, a01);
    a10 = MFMA16(Wf[cur][2].v, bhi[1].v, a10);
    a11 = MFMA16(Wf[cur][3].v, bhi[1].v, a11);
    a00 = MFMA16(Wf[cur][0].v, blo[0].v, a00);
    a01 = MFMA16(Wf[cur][1].v, blo[0].v, a01);
    a10 = MFMA16(Wf[cur][0].v, blo[1].v, a10);
    a11 = MFMA16(Wf[cur][1].v, blo[1].v, a11);

    // relu + trunc-split; D reg r of accX0 -> slot j=r, accX1 -> slot 4+r
    split2(fmaxf(a00[0], 0.f), fmaxf(a00[1], 0.f), bhi[0].i[0], blo[0].i[0]);
    split2(fmaxf(a00[2], 0.f), fmaxf(a00[3], 0.f), bhi[0].i[1], blo[0].i[1]);
    split2(fmaxf(a01[0], 0.f), fmaxf(a01[1], 0.f), bhi[0].i[2], blo[0].i[2]);
    split2(fmaxf(a01[2], 0.f), fmaxf(a01[3], 0.f), bhi[0].i[3], blo[0].i[3]);
    split2(fmaxf(a10[0], 0.f), fmaxf(a10[1], 0.f), bhi[1].i[0], blo[1].i[0]);
    split2(fmaxf(a10[2], 0.f), fmaxf(a10[3], 0.f), bhi[1].i[1], blo[1].i[1]);
    split2(fmaxf(a11[0], 0.f), fmaxf(a11[1], 0.f), bhi[1].i[2], blo[1].i[2]);
    split2(fmaxf(a11[2], 0.f), fmaxf(a11[3], 0.f), bhi[1].i[3], blo[1].i[3]);

    // ---- PIN (rule #17): force the l+1 fragments to be complete, live
    // registers HERE -- the compiler can no longer sink the ds_reads into
    // iteration l+1; their lgkmcnt wait sits after ~500 cyc of compute.
    asm volatile("" : "+v"(Wf[nxt][0].q), "+v"(Wf[nxt][1].q),
                      "+v"(Wf[nxt][2].q), "+v"(Wf[nxt][3].q),
                      "+v"(Cf[nxt][0].v), "+v"(Cf[nxt][1].v));
  }

  // ---- final layer l=40 (parity 0 buffer). W rows 16-31 zero: only frags
  // 0 (hi, rows 0-15) and 2 (lo) + bias c0 needed; row0 = W_out.
  float res0, res1;
  {
    f32x4 a00 = MFMA16(Wf[0][0].v, bhi[0].v, Cf[0][0].v);
    f32x4 a10 = MFMA16(Wf[0][0].v, bhi[1].v, Cf[0][0].v);
    a00 = MFMA16(Wf[0][2].v, bhi[0].v, a00);
    a10 = MFMA16(Wf[0][2].v, bhi[1].v, a10);
    a00 = MFMA16(Wf[0][0].v, blo[0].v, a00);
    a10 = MFMA16(Wf[0][0].v, blo[1].v, a10);
    res0 = a00[0];  // row 0 lives in reg 0 of lanes g==0 (lane<16)
    res1 = a10[0];
  }

  if (lane < 16) {
    out[bbase + n] = res0;
    out[bbase + 16 + n] = res1;
  }
}

extern "C" void kernel_launch(void* const* d_in, const int* in_sizes, int n_in,
                              void* d_out, int out_size, void* d_ws, size_t ws_size,
                              hipStream_t stream) {
  const float* state = (const float*)d_in[0];
  const float* Wh    = (const float*)d_in[1];
  const float* bh    = (const float*)d_in[2];
  const float* Wout  = (const float*)d_in[3];
  const float* bout  = (const float*)d_in[4];
  float* out = (float*)d_out;

  build_tables<<<NL + 1, 64, 0, stream>>>(Wh, bh, Wout, bout, (char*)d_ws);

  // 4096 waves; 16 waves (1024 thr) per block; 256 blocks = 1/CU (LDS-pinned).
  policy_mfma<<<256, 1024, LDS_BYTES, stream>>>(state, (const char*)d_ws, out);
}

// Round 20
// 44.786 us; speedup vs baseline: 1.0394x; 1.0047x over previous
//
#include <hip/hip_runtime.h>

// Policy MLP via split-precision bf16 MFMA (round 20: 32x32 shape + bias-MFMA
// + LDS, consolidated sum-reduction).
// B=131072, D=32, L=40 hidden + final 32->1.
//
// r5-r19 (12 experiments) establish: wall == SUM of pipe demands; overlap
// engineering is futile at HIP level. This round shrinks the sum:
//  * 32x32x16 single-acc form (r3-verified pi/repack): 7 MFMAs/wave-layer
//    (1 bias-MFMA + 6 product) at the faster 32x32 rate.
//  * bias C-table (2x b128 LDS reads) replaced by 1x b32 packed bf16 hi/lo
//    feeding the bias-MFMA (ones-trick, r2/r3-verified).
//  * LDS per wave-layer: 4x b128 + 1x b32 (was 6x b128).
//  * Base infra from r13: 157KB LDS staging (38 layers + compact bias),
//    double-buffered register prefetch, trunc-split via v_perm_b32, full
//    unroll, C=32 cols/wave, 16 waves/CU (1024-thr block, 1 block/CU).
//
// Math per layer: acc = bias (via MFMA) + Whi*xhi + Wlo*xhi + Whi*xlo.
// pi(kk,h,w,e) = 16kk + 8(w>>1) + 4h + 2(w&1) + e on both A and B => D's
// natural reg layout feeds the next layer's B slots in-lane (r3-verified).

#define NB 131072
#define DD 32
#define NL 40
#define BIAS_BYTES ((NL + 1) * 32 * 4)       // 5248: packed bf16 hi|lo dwords
#define WTAB_OFF   BIAS_BYTES
#define LDS_LAYERS 38
#define LDS_BYTES  (BIAS_BYTES + LDS_LAYERS * 4096)  // 160896 <= 163840

typedef short bf16x8 __attribute__((ext_vector_type(8)));
typedef float f32x16 __attribute__((ext_vector_type(16)));

union Frag { int4 q; int i[4]; bf16x8 v; };

__device__ inline unsigned f2bf(float f) {  // fp32 -> bf16 bits, RNE
  unsigned u = __float_as_uint(f);
  return (u + 0x7fffu + ((u >> 16) & 1u)) >> 16;
}
__device__ inline float bf2f(unsigned s) { return __int_as_float((int)(s << 16)); }

// ---- table build ----------------------------------------------------------
// d_ws layout: [compact bias 5248 B][wtab 41 layers x 4096 B].
// wtab[l][g][lane]: g=0/1: W hi (kk=0/1); g=2/3: W lo. pi-permuted k order.
// btab[l][m] (m=0..31): bias_hi | bias_lo<<16 (bf16 pair) for output row m.
__global__ __launch_bounds__(64) void build_tables(
    const float* __restrict__ Wh, const float* __restrict__ bh,
    const float* __restrict__ Wout, const float* __restrict__ bout,
    char* __restrict__ ws) {
  const int l = blockIdx.x;      // 0..40 (40 == output layer)
  const int lane = threadIdx.x;  // 0..63
  const int m = lane & 31, h = lane >> 5;
  int4* wtab = (int4*)(ws + WTAB_OFF);
  int* bc = (int*)ws;
  for (int g = 0; g < 4; ++g) {  // {hi,lo} x {kk}
    const int kk = g & 1;
    const bool lopart = (g >= 2);
    int wds[4];
    for (int w = 0; w < 4; ++w) {
      const int k = 16 * kk + 8 * (w >> 1) + 4 * h + 2 * (w & 1);  // pi
      float a, b;
      if (l < NL) {
        a = Wh[(l * 32 + m) * 32 + k];
        b = Wh[(l * 32 + m) * 32 + k + 1];
      } else {  // final layer: row 0 = W_out, rest zero
        a = (m == 0) ? Wout[k] : 0.f;
        b = (m == 0) ? Wout[k + 1] : 0.f;
      }
      unsigned ah = f2bf(a), bhh = f2bf(b);
      unsigned al = f2bf(a - bf2f(ah)), bl = f2bf(b - bf2f(bhh));
      wds[w] = lopart ? (int)(al | (bl << 16)) : (int)(ah | (bhh << 16));
    }
    wtab[(l * 4 + g) * 64 + lane] = make_int4(wds[0], wds[1], wds[2], wds[3]);
  }
  if (lane < 32) {  // compact packed bias (bf16 hi + lo)
    float bv = (l < NL) ? bh[l * 32 + lane] : ((lane == 0) ? bout[0] : 0.f);
    unsigned bhi = f2bf(bv);
    unsigned blo = f2bf(bv - bf2f(bhi));
    bc[l * 32 + lane] = (int)(bhi | (blo << 16));
  }
}

// ---- main kernel ----------------------------------------------------------
// Truncation split: hi = packed high-halves of (a,b) via one v_perm_b32;
// lo = packed high-halves of the exact residuals (x = hi + lo to 2^-16).
__device__ inline void split2(float a, float b, int& hi, int& lo) {
  const unsigned ia = __float_as_uint(a), ib = __float_as_uint(b);
  hi = (int)__builtin_amdgcn_perm(ia, ib, 0x03020706u);
  const float ha = __int_as_float((int)(ia & 0xffff0000u));
  const float hb = __int_as_float((int)(ib & 0xffff0000u));
  const float la = a - ha, lb = b - hb;  // exact
  lo = (int)__builtin_amdgcn_perm(__float_as_uint(la), __float_as_uint(lb),
                                  0x03020706u);
}

#define MFMA32(A, B, C) __builtin_amdgcn_mfma_f32_32x32x16_bf16((A), (B), (C), 0, 0, 0)

__global__ __launch_bounds__(1024, 4) void policy_mfma(
    const float* __restrict__ state, const char* __restrict__ tab,
    float* __restrict__ out) {
  extern __shared__ char smem[];
  const int tid = threadIdx.x;
  const int lane = tid & 63;
  const int n = lane & 31, h = lane >> 5;
  const int wid = blockIdx.x * 16 + (tid >> 6);
  const int bbase = wid * 32;  // 32 batch cols per wave, one 32x32 acc

  // ---- stage compact bias + 38 layers of weights into LDS (one-time) ----
  {
    const int4* src = (const int4*)tab;
    int4* dst = (int4*)smem;
    for (int i = tid; i < LDS_BYTES / 16; i += 1024) dst[i] = src[i];
  }

  // Layer-0 B frags (pi layout, r3-verified):
  // (kk, h, w=0,1) <- x[16kk+4h+0..3]; (w=2,3) <- x[16kk+8+4h+0..3]
  Frag bhi0, bhi1, blo0, blo1;
  {
    const float* xr = state + (size_t)(bbase + n) * DD;
    float4 xa = *(const float4*)(xr + 4 * h);
    float4 xb = *(const float4*)(xr + 8 + 4 * h);
    float4 xc = *(const float4*)(xr + 16 + 4 * h);
    float4 xd = *(const float4*)(xr + 24 + 4 * h);
    split2(xa.x, xa.y, bhi0.i[0], blo0.i[0]);
    split2(xa.z, xa.w, bhi0.i[1], blo0.i[1]);
    split2(xb.x, xb.y, bhi0.i[2], blo0.i[2]);
    split2(xb.z, xb.w, bhi0.i[3], blo0.i[3]);
    split2(xc.x, xc.y, bhi1.i[0], blo1.i[0]);
    split2(xc.z, xc.w, bhi1.i[1], blo1.i[1]);
    split2(xd.x, xd.y, bhi1.i[2], blo1.i[2]);
    split2(xd.z, xd.w, bhi1.i[3], blo1.i[3]);
  }

  Frag bones;  // bias-MFMA B: positional slots (h=0, w=0, e=0,1) = 1.0
  bones.i[0] = (h == 0) ? 0x3F803F80 : 0;
  bones.i[1] = bones.i[2] = bones.i[3] = 0;
  const int hmask = (h == 0) ? -1 : 0;  // bias A-frag lives in h==0 lanes

  __syncthreads();  // LDS tables ready

  const int4* lw = (const int4*)(smem + WTAB_OFF) + lane;  // LDS weights l<38
  const int* bc = (const int*)smem;                         // compact bias
  const int4* gw = (const int4*)(tab + WTAB_OFF) + lane;    // global l>=38

  const f32x16 zero16 = {0, 0, 0, 0, 0, 0, 0, 0, 0, 0, 0, 0, 0, 0, 0, 0};

  // Double-buffered register prefetch (parity; full unroll => static idx).
  Frag Wf[2][4];
  int nb[2];
  Wf[0][0].q = lw[0];
  Wf[0][1].q = lw[64];
  Wf[0][2].q = lw[128];
  Wf[0][3].q = lw[192];
  nb[0] = bc[n];

#pragma unroll
  for (int l = 0; l < NL; ++l) {
    const int cur = l & 1, nxt = cur ^ 1;

    // ---- prefetch layer l+1 fragments ----
    {
      const int lp = l + 1;
      const int4* src = (lp < LDS_LAYERS) ? lw : gw;  // compile-time per iter
      Wf[nxt][0].q = src[lp * 256 + 0];
      Wf[nxt][1].q = src[lp * 256 + 64];
      Wf[nxt][2].q = src[lp * 256 + 128];
      Wf[nxt][3].q = src[lp * 256 + 192];
      nb[nxt] = bc[lp * 32 + n];
    }

    // ---- compute layer l: bias-MFMA + 6 product MFMAs (one 32x32 acc) ----
    Frag ab;
    ab.i[0] = nb[cur] & hmask;
    ab.i[1] = ab.i[2] = ab.i[3] = 0;
    f32x16 acc = MFMA32(ab.v, bones.v, zero16);
    acc = MFMA32(Wf[cur][0].v, bhi0.v, acc);  // hi x hi, kk=0
    acc = MFMA32(Wf[cur][2].v, bhi0.v, acc);  // lo x hi, kk=0
    acc = MFMA32(Wf[cur][1].v, bhi1.v, acc);  // hi x hi, kk=1
    acc = MFMA32(Wf[cur][3].v, bhi1.v, acc);  // lo x hi, kk=1
    acc = MFMA32(Wf[cur][0].v, blo0.v, acc);  // hi x lo, kk=0
    acc = MFMA32(Wf[cur][1].v, blo1.v, acc);  // hi x lo, kk=1

    // relu + trunc-split; reg-pair p -> B slot (kk=p>>2, w=p&3) [r3-verified]
#pragma unroll
    for (int p = 0; p < 8; ++p) {
      float a = fmaxf(acc[2 * p], 0.f);
      float b = fmaxf(acc[2 * p + 1], 0.f);
      int hi, lo;
      split2(a, b, hi, lo);
      if (p < 4) { bhi0.i[p] = hi; blo0.i[p] = lo; }
      else       { bhi1.i[p - 4] = hi; blo1.i[p - 4] = lo; }
    }
  }

  // ---- final layer l=40 (parity 0 buffer): same 7-MFMA body, no relu ----
  float res;
  {
    Frag ab;
    ab.i[0] = nb[0] & hmask;
    ab.i[1] = ab.i[2] = ab.i[3] = 0;
    f32x16 acc = MFMA32(ab.v, bones.v, zero16);
    acc = MFMA32(Wf[0][0].v, bhi0.v, acc);
    acc = MFMA32(Wf[0][2].v, bhi0.v, acc);
    acc = MFMA32(Wf[0][1].v, bhi1.v, acc);
    acc = MFMA32(Wf[0][3].v, bhi1.v, acc);
    acc = MFMA32(Wf[0][0].v, blo0.v, acc);
    acc = MFMA32(Wf[0][1].v, blo1.v, acc);
    res = acc[0];  // D row 0 lives in reg 0 of h==0 lanes (r3-verified)
  }

  if (h == 0) out[bbase + n] = res;
}

extern "C" void kernel_launch(void* const* d_in, const int* in_sizes, int n_in,
                              void* d_out, int out_size, void* d_ws, size_t ws_size,
                              hipStream_t stream) {
  const float* state = (const float*)d_in[0];
  const float* Wh    = (const float*)d_in[1];
  const float* bh    = (const float*)d_in[2];
  const float* Wout  = (const float*)d_in[3];
  const float* bout  = (const float*)d_in[4];
  float* out = (float*)d_out;

  build_tables<<<NL + 1, 64, 0, stream>>>(Wh, bh, Wout, bout, (char*)d_ws);

  // 4096 waves; 16 waves (1024 thr) per block; 256 blocks = 1/CU (LDS-pinned).
  policy_mfma<<<256, 1024, LDS_BYTES, stream>>>(state, (const char*)d_ws, out);
}